// Round 2
// baseline (932.372 us; speedup 1.0000x reference)
//
#include <hip/hip_runtime.h>
#include <cstdint>
#include <cstddef>

// Problem constants (B,H,W,C)=(4,128,128,512), HID=768, HEADS=8, BS=8
#define Bb     4
#define Cc     512
#define HID    768
#define HEADS  8
#define NBW    16
#define NBT    256
#define BS2    64
#define HD     96
#define HWTOK  16384
#define MTOK   65536
#define N3     2304

typedef __attribute__((ext_vector_type(8))) short frag16;
typedef __attribute__((ext_vector_type(4))) float f32x4;

__device__ __forceinline__ float b2f(unsigned short u) {
    union { unsigned int i; float f; } x; x.i = ((unsigned int)u) << 16; return x.f;
}
__device__ __forceinline__ unsigned short f2b(float f) {
    union { float f; unsigned int i; } x; x.f = f;
    unsigned int r = x.i + 0x7fffu + ((x.i >> 16) & 1u);   // RNE
    return (unsigned short)(r >> 16);
}
union cvt8 { uint4 u; unsigned short s[8]; };

// ---------------- kernel 0: weight transpose fp32 -> bf16 (B^T) ------------
__global__ __launch_bounds__(256) void k_transpose(
    const float* __restrict__ w, unsigned short* __restrict__ wt,
    int K, int N) {
    int e = blockIdx.x * 256 + threadIdx.x;
    if (e < K * N) {
        int k = e / N, n = e - k * N;
        wt[(size_t)n * K + k] = f2b(w[e]);
    }
}

// ---------------- kernel 1: gather + in_proj + GLU -------------------------
// p = x[b, idx[hw], :] @ W_in  (3 slices s,v,y share the A tile)
// vt = v*tanh(s) -> block layout (HEADS,B,NBT,BS2,HD); y -> (MTOK,HID) bf16
__global__ __launch_bounds__(256) void k_inproj(
    const float* __restrict__ x,
    const unsigned short* __restrict__ winT,   // (2304, 512) bf16
    const float* __restrict__ b_in,            // (2304)
    const int* __restrict__ idx,               // (16384)
    unsigned short* __restrict__ y_img,        // (MTOK, HID) bf16
    unsigned short* __restrict__ vt_blk) {     // (HEADS,B,NBT,BS2,HD) bf16
    __shared__ alignas(16) unsigned short As[64][40];
    __shared__ alignas(16) unsigned short Bs[3][64][40];
    const int tid  = threadIdx.x;
    const int wv   = tid >> 6;
    const int lane = tid & 63;
    const int n0 = blockIdx.x * 64;     // j-column base in [0,768)
    const int m0 = blockIdx.y * 64;     // token base

    // staging: 64x32 tile = 256 threads x 8 elems
    const int a_m = tid >> 2, a_k = (tid & 3) * 8;
    const int t_a = m0 + a_m;
    const int bb_a = t_a >> 14, hw_a = t_a & 16383;
    const float* a_src = x + ((size_t)bb_a * HWTOK + idx[hw_a]) * Cc + a_k;
    const int b_n = tid >> 2, b_k = (tid & 3) * 8;

    const int fr = lane & 15, q = lane >> 4;

    f32x4 acc[3][4];
    #pragma unroll
    for (int s = 0; s < 3; s++)
        #pragma unroll
        for (int n = 0; n < 4; n++) acc[s][n] = (f32x4){0.f, 0.f, 0.f, 0.f};

    for (int k0 = 0; k0 < Cc; k0 += 32) {
        float4 f0 = *(const float4*)(a_src + k0);
        float4 f1 = *(const float4*)(a_src + k0 + 4);
        cvt8 c;
        c.s[0] = f2b(f0.x); c.s[1] = f2b(f0.y); c.s[2] = f2b(f0.z); c.s[3] = f2b(f0.w);
        c.s[4] = f2b(f1.x); c.s[5] = f2b(f1.y); c.s[6] = f2b(f1.z); c.s[7] = f2b(f1.w);
        *(uint4*)(&As[a_m][a_k]) = c.u;
        #pragma unroll
        for (int sl = 0; sl < 3; sl++) {
            const unsigned short* bsrc =
                winT + ((size_t)(sl * HID + n0 + b_n)) * Cc + k0 + b_k;
            *(uint4*)(&Bs[sl][b_n][b_k]) = *(const uint4*)bsrc;
        }
        __syncthreads();
        frag16 af = *(const frag16*)(&As[wv * 16 + fr][q * 8]);
        #pragma unroll
        for (int nt = 0; nt < 4; nt++) {
            #pragma unroll
            for (int sl = 0; sl < 3; sl++) {
                frag16 bf = *(const frag16*)(&Bs[sl][nt * 16 + fr][q * 8]);
                acc[sl][nt] =
                    __builtin_amdgcn_mfma_f32_16x16x32_bf16(af, bf, acc[sl][nt], 0, 0, 0);
            }
        }
        __syncthreads();
    }

    // epilogue: GLU + layout writes
    #pragma unroll
    for (int nt = 0; nt < 4; nt++) {
        const int j  = n0 + nt * 16 + fr;
        const float bsv = b_in[j];
        const float bvv = b_in[HID + j];
        const float byv = b_in[2 * HID + j];
        const int h = j / HD;
        const int d = j - h * HD;
        #pragma unroll
        for (int r = 0; r < 4; r++) {
            const int t  = m0 + wv * 16 + q * 4 + r;
            const int bb = t >> 14;
            const int hw = t & 16383;
            const float sv = acc[0][nt][r] + bsv;
            const float vv = acc[1][nt][r] + bvv;
            const float yv = acc[2][nt][r] + byv;
            const float vt = vv * tanhf(sv);
            y_img[(size_t)t * HID + j] = f2b(yv);
            const int hr = hw >> 7, wc = hw & 127;
            const int nblk = ((hr >> 3) << 4) | (wc >> 3);
            const int ii   = ((hr & 7) << 3) | (wc & 7);
            const size_t off =
                ((((size_t)h * Bb + bb) * NBT + nblk) * BS2 + ii) * HD + d;
            vt_blk[off] = f2b(vt);
        }
    }
}

// ---------------- kernel 2: block attention + y multiply (in-place) --------
// av[i,d] = sum_j attn[g,i,j] * vt[g,j,d];  y_img <- av * y_img
__global__ __launch_bounds__(256) void k_attn(
    const float* __restrict__ attnw,            // (HEADS,B,NBT,64,64) fp32
    const unsigned short* __restrict__ vt_blk,  // (HEADS,B,NBT,64,96) bf16
    unsigned short* __restrict__ y_img) {       // (MTOK,HID) bf16, in/out
    __shared__ alignas(16) unsigned short Aw[64][72];   // padded vs stride-64
    __shared__ alignas(16) unsigned short Vt[64 * 96];
    const int tid = threadIdx.x;
    const int g = blockIdx.x;                   // (h*B + b)*NBT + n
    const float* asrc = attnw + (size_t)g * 4096;
    const unsigned short* vsrc = vt_blk + (size_t)g * 6144;
    #pragma unroll
    for (int r = 0; r < 2; r++) {               // 512 chunks of 8 floats
        int v = tid + 256 * r;
        int i = v >> 3, j = (v & 7) * 8;
        const float* ap = asrc + (size_t)v * 8;
        float4 f0 = *(const float4*)(ap);
        float4 f1 = *(const float4*)(ap + 4);
        cvt8 c;
        c.s[0] = f2b(f0.x); c.s[1] = f2b(f0.y); c.s[2] = f2b(f0.z); c.s[3] = f2b(f0.w);
        c.s[4] = f2b(f1.x); c.s[5] = f2b(f1.y); c.s[6] = f2b(f1.z); c.s[7] = f2b(f1.w);
        *(uint4*)(&Aw[i][j]) = c.u;
    }
    #pragma unroll
    for (int r = 0; r < 3; r++)                 // 768 uint4 (bf16 ws)
        ((uint4*)Vt)[tid + 256 * r] = ((const uint4*)vsrc)[tid + 256 * r];
    __syncthreads();

    const int i  = tid >> 2;                    // row 0..63
    const int dg = (tid & 3) * 24;              // head-dim chunk
    float accr[24];
    #pragma unroll
    for (int dd = 0; dd < 24; dd++) accr[dd] = 0.f;
    for (int j = 0; j < 64; j++) {
        const float aw = b2f(Aw[i][j]);
        const unsigned short* vrow = &Vt[j * 96 + dg];
        #pragma unroll
        for (int dd = 0; dd < 24; dd++) accr[dd] += aw * b2f(vrow[dd]);
    }
    const int h = g >> 10;
    const int b = (g >> 8) & 3;
    const int n = g & 255;
    const int hr = ((n >> 4) << 3) | (i >> 3);
    const int wc = ((n & 15) << 3) | (i & 7);
    const size_t t = ((size_t)b << 14) + (size_t)hr * 128 + wc;
    const size_t base = t * HID + (size_t)h * HD + dg;
    #pragma unroll
    for (int dd = 0; dd < 24; dd++) {
        const float yv = b2f(y_img[base + dd]);
        y_img[base + dd] = f2b(accr[dd] * yv);   // same-thread read->write, no race
    }
}

// ---------------- kernel 3: out_proj + bias + scatter ----------------------
__global__ __launch_bounds__(256) void k_outproj(
    const unsigned short* __restrict__ avy,     // (MTOK,HID) bf16 (=y_img)
    const unsigned short* __restrict__ woutT,   // (512, 768) bf16
    const float* __restrict__ b_out,            // (512)
    const int* __restrict__ idx,
    float* __restrict__ out) {                  // (B,HW,C) fp32
    __shared__ alignas(16) unsigned short As[64][40];
    __shared__ alignas(16) unsigned short Bs[64][40];
    const int tid  = threadIdx.x;
    const int wv   = tid >> 6;
    const int lane = tid & 63;
    const int c0 = blockIdx.x * 64;
    const int m0 = blockIdx.y * 64;
    const int a_m = tid >> 2, a_k = (tid & 3) * 8;
    const unsigned short* a_src = avy + (size_t)(m0 + a_m) * HID + a_k;
    const int b_n = tid >> 2, b_k = (tid & 3) * 8;
    const int fr = lane & 15, q = lane >> 4;

    f32x4 acc[4];
    #pragma unroll
    for (int nt = 0; nt < 4; nt++) acc[nt] = (f32x4){0.f, 0.f, 0.f, 0.f};

    for (int k0 = 0; k0 < HID; k0 += 32) {
        *(uint4*)(&As[a_m][a_k]) = *(const uint4*)(a_src + k0);
        *(uint4*)(&Bs[b_n][b_k]) =
            *(const uint4*)(woutT + (size_t)(c0 + b_n) * HID + k0 + b_k);
        __syncthreads();
        frag16 af = *(const frag16*)(&As[wv * 16 + fr][q * 8]);
        #pragma unroll
        for (int nt = 0; nt < 4; nt++) {
            frag16 bf = *(const frag16*)(&Bs[nt * 16 + fr][q * 8]);
            acc[nt] = __builtin_amdgcn_mfma_f32_16x16x32_bf16(af, bf, acc[nt], 0, 0, 0);
        }
        __syncthreads();
    }
    #pragma unroll
    for (int nt = 0; nt < 4; nt++) {
        const int c = c0 + nt * 16 + fr;
        const float bo = b_out[c];
        #pragma unroll
        for (int r = 0; r < 4; r++) {
            const int t  = m0 + wv * 16 + q * 4 + r;
            const int bb = t >> 14;
            const int hw = t & 16383;
            const int dst = idx[hw];
            out[((size_t)bb * HWTOK + dst) * Cc + c] = acc[nt][r] + bo;
        }
    }
}

extern "C" void kernel_launch(void* const* d_in, const int* in_sizes, int n_in,
                              void* d_out, int out_size, void* d_ws, size_t ws_size,
                              hipStream_t stream) {
    const float* x     = (const float*)d_in[0];
    const float* attnw = (const float*)d_in[1];
    const float* W_in  = (const float*)d_in[2];
    const float* b_in  = (const float*)d_in[3];
    const float* W_out = (const float*)d_in[4];
    const float* b_out = (const float*)d_in[5];
    const int*   idx   = (const int*)d_in[6];
    float*       out   = (float*)d_out;

    // workspace carve-up (total ~204.5 MB)
    char* p = (char*)d_ws;
    unsigned short* winT  = (unsigned short*)p; p += (size_t)N3 * Cc * 2;       // 2.36 MB
    unsigned short* woutT = (unsigned short*)p; p += (size_t)Cc * HID * 2;      // 0.79 MB
    unsigned short* vt    = (unsigned short*)p; p += (size_t)HEADS * Bb * NBT * BS2 * HD * 2; // 100.7 MB
    unsigned short* y_img = (unsigned short*)p; p += (size_t)MTOK * HID * 2;    // 100.7 MB (avy in-place)

    k_transpose<<<(N3 * Cc + 255) / 256, 256, 0, stream>>>(W_in, winT, Cc, N3);
    k_transpose<<<(HID * Cc + 255) / 256, 256, 0, stream>>>(W_out, woutT, HID, Cc);

    dim3 g1(HID / 64, MTOK / 64);   // (12, 1024)
    k_inproj<<<g1, 256, 0, stream>>>(x, winT, b_in, idx, y_img, vt);

    k_attn<<<HEADS * Bb * NBT, 256, 0, stream>>>(attnw, vt, y_img);

    dim3 g3(Cc / 64, MTOK / 64);    // (8, 1024)
    k_outproj<<<g3, 256, 0, stream>>>(y_img, woutT, b_out, idx, out);
}

// Round 3
// 921.421 us; speedup vs baseline: 1.0119x; 1.0119x over previous
//
#include <hip/hip_runtime.h>
#include <cstdint>
#include <cstddef>

// Problem constants (B,H,W,C)=(4,128,128,512), HID=768, HEADS=8, BS=8
#define Bb     4
#define Cc     512
#define HID    768
#define HEADS  8
#define NBT    256
#define BS2    64
#define HD     96
#define HWTOK  16384
#define MTOK   65536
#define N3     2304

typedef __attribute__((ext_vector_type(8))) short frag16;
typedef __attribute__((ext_vector_type(4))) float f32x4;

__device__ __forceinline__ float b2f(unsigned short u) {
    union { unsigned int i; float f; } x; x.i = ((unsigned int)u) << 16; return x.f;
}
__device__ __forceinline__ unsigned short f2b(float f) {
    union { float f; unsigned int i; } x; x.f = f;
    unsigned int r = x.i + 0x7fffu + ((x.i >> 16) & 1u);   // RNE
    return (unsigned short)(r >> 16);
}
union cvt8 { uint4 u; unsigned short s[8]; };

__device__ __forceinline__ void gl2lds16(const void* g, void* l) {
    __builtin_amdgcn_global_load_lds(
        (const __attribute__((address_space(1))) unsigned int*)g,
        (__attribute__((address_space(3))) unsigned int*)l, 16, 0, 0);
}

// ---------------- kernel 0: weight transpose fp32 -> bf16 (B^T) ------------
__global__ __launch_bounds__(256) void k_transpose(
    const float* __restrict__ w, unsigned short* __restrict__ wt,
    int K, int N) {
    int e = blockIdx.x * 256 + threadIdx.x;
    if (e < K * N) {
        int k = e / N, n = e - k * N;
        wt[(size_t)n * K + k] = f2b(w[e]);
    }
}

// ---------------- kernel 0b: gather + fp32->bf16 convert of x --------------
__global__ __launch_bounds__(256) void k_gather(
    const float* __restrict__ x, const int* __restrict__ idx,
    unsigned short* __restrict__ xg) {          // (MTOK, 512) bf16
    int gid = blockIdx.x * 256 + threadIdx.x;   // MTOK*64 chunks of 8
    int t = gid >> 6, col = (gid & 63) * 8;
    int bb = t >> 14, hw = t & 16383;
    const float* src = x + ((size_t)bb * HWTOK + idx[hw]) * Cc + col;
    float4 f0 = *(const float4*)src, f1 = *(const float4*)(src + 4);
    cvt8 c;
    c.s[0] = f2b(f0.x); c.s[1] = f2b(f0.y); c.s[2] = f2b(f0.z); c.s[3] = f2b(f0.w);
    c.s[4] = f2b(f1.x); c.s[5] = f2b(f1.y); c.s[6] = f2b(f1.z); c.s[7] = f2b(f1.w);
    *(uint4*)(xg + (size_t)t * Cc + col) = c.u;
}

// ---------------- kernel 1: in_proj + GLU (m97 structure) ------------------
// 128m x (64n x 3 slices) tile; A=xg (bf16), B=winT; DMA staging.
__global__ __launch_bounds__(256) void k_inproj(
    const unsigned short* __restrict__ xg,     // (MTOK, 512) bf16
    const unsigned short* __restrict__ winT,   // (2304, 512) bf16
    const float* __restrict__ b_in,            // (2304) fp32
    unsigned short* __restrict__ y_img,        // (MTOK, HID) bf16
    unsigned short* __restrict__ vt_blk) {     // (HEADS,B,NBT,BS2,HD) bf16
    // LDS: A 128x32 @0 (8KB), B 3x64x32 @4096 shorts (12KB) — unpadded (DMA)
    __shared__ alignas(16) unsigned short smem[4096 + 6144];
    const int tid = threadIdx.x;
    const int wv = tid >> 6, lane = tid & 63;
    const int wm = wv >> 1, wn = wv & 1;
    const int fr = lane & 15, q = lane >> 4;
    const int n0 = blockIdx.x * 64;     // per-slice col base [0,768)
    const int m0 = blockIdx.y * 128;

    // 20 DMA chunks of 1024B (A:0-7, B:8-19), 5 per wave
    const char* gbase[5];
    unsigned short* lbase[5];
    #pragma unroll
    for (int ci = 0; ci < 5; ci++) {
        int c = wv * 5 + ci;
        if (c < 8) {
            int row = c * 16 + (lane >> 2);
            gbase[ci] = (const char*)(xg + (size_t)(m0 + row) * Cc + (lane & 3) * 8);
            lbase[ci] = smem + c * 512;
        } else {
            int cb = c - 8, sl = cb >> 2, qc = cb & 3;
            int row = qc * 16 + (lane >> 2);
            gbase[ci] = (const char*)(winT + (size_t)(sl * HID + n0 + row) * Cc + (lane & 3) * 8);
            lbase[ci] = smem + 4096 + cb * 512;
        }
    }

    f32x4 acc[3][2][4];
    #pragma unroll
    for (int sl = 0; sl < 3; sl++)
        #pragma unroll
        for (int nt = 0; nt < 2; nt++)
            #pragma unroll
            for (int mt = 0; mt < 4; mt++) acc[sl][nt][mt] = (f32x4){0.f,0.f,0.f,0.f};

    for (int k0 = 0; k0 < Cc; k0 += 32) {
        #pragma unroll
        for (int ci = 0; ci < 5; ci++)
            gl2lds16(gbase[ci] + (size_t)k0 * 2, lbase[ci]);
        __syncthreads();
        frag16 af[4];
        #pragma unroll
        for (int mt = 0; mt < 4; mt++)
            af[mt] = *(const frag16*)(smem + (wm * 64 + mt * 16 + fr) * 32 + q * 8);
        #pragma unroll
        for (int sl = 0; sl < 3; sl++) {
            #pragma unroll
            for (int nt = 0; nt < 2; nt++) {
                frag16 bf = *(const frag16*)(smem + 4096 + sl * 2048 +
                                             (wn * 32 + nt * 16 + fr) * 32 + q * 8);
                #pragma unroll
                for (int mt = 0; mt < 4; mt++)
                    acc[sl][nt][mt] = __builtin_amdgcn_mfma_f32_16x16x32_bf16(
                        af[mt], bf, acc[sl][nt][mt], 0, 0, 0);
            }
        }
        __syncthreads();
    }

    // epilogue: GLU + layout writes
    #pragma unroll
    for (int nt = 0; nt < 2; nt++) {
        const int j = n0 + wn * 32 + nt * 16 + fr;
        const float bs = b_in[j], bv = b_in[HID + j], by = b_in[2 * HID + j];
        const int h = j / HD, d = j - h * HD;
        #pragma unroll
        for (int mt = 0; mt < 4; mt++) {
            #pragma unroll
            for (int r = 0; r < 4; r++) {
                const int t = m0 + wm * 64 + mt * 16 + q * 4 + r;
                const int bb = t >> 14, hw = t & 16383;
                const float sv = acc[0][nt][mt][r] + bs;
                const float vv = acc[1][nt][mt][r] + bv;
                const float yv = acc[2][nt][mt][r] + by;
                y_img[(size_t)t * HID + j] = f2b(yv);
                const int hr = hw >> 7, wc = hw & 127;
                const int nblk = ((hr >> 3) << 4) | (wc >> 3);
                const int ii   = ((hr & 7) << 3) | (wc & 7);
                vt_blk[((((size_t)h * Bb + bb) * NBT + nblk) * BS2 + ii) * HD + d] =
                    f2b(vv * tanhf(sv));
            }
        }
    }
}

// ---------------- kernel 2: block attention (MFMA) + y multiply ------------
// av[i,d] = sum_j attn[g,i,j] * vt[g,j,d];  y_img <- av * y_img (in place)
__global__ __launch_bounds__(256) void k_attn(
    const float* __restrict__ attnw,            // (HEADS,B,NBT,64,64) fp32
    const unsigned short* __restrict__ vt_blk,  // (HEADS,B,NBT,64,96) bf16
    unsigned short* __restrict__ y_img) {       // (MTOK,HID) bf16, in/out
    __shared__ alignas(16) unsigned short Aat[64][72];   // attn bf16, padded
    __shared__ alignas(16) unsigned short VtT[96][72];   // vt transposed (B^T)
    const int tid = threadIdx.x;
    const int g = blockIdx.x;                   // (h*B + b)*NBT + n
    const int wv = tid >> 6, lane = tid & 63;
    const int fr = lane & 15, q = lane >> 4;
    const int wm = wv >> 1, wn = wv & 1;

    const float* asrc = attnw + (size_t)g * 4096;
    const unsigned short* vsrc = vt_blk + (size_t)g * 6144;
    #pragma unroll
    for (int r = 0; r < 2; r++) {               // attn: 512 chunks of 8 floats
        int v = tid + 256 * r;
        int i = v >> 3, jj = (v & 7) * 8;
        const float* ap = asrc + (size_t)v * 8;
        float4 f0 = *(const float4*)ap, f1 = *(const float4*)(ap + 4);
        cvt8 c;
        c.s[0]=f2b(f0.x); c.s[1]=f2b(f0.y); c.s[2]=f2b(f0.z); c.s[3]=f2b(f0.w);
        c.s[4]=f2b(f1.x); c.s[5]=f2b(f1.y); c.s[6]=f2b(f1.z); c.s[7]=f2b(f1.w);
        *(uint4*)(&Aat[i][jj]) = c.u;
    }
    #pragma unroll
    for (int r = 0; r < 3; r++) {               // vt: 768 uint4, transpose
        int v = tid + 256 * r;
        int j = v / 12, dq = v - j * 12;
        cvt8 c; c.u = ((const uint4*)vsrc)[v];
        #pragma unroll
        for (int e = 0; e < 8; e++) VtT[dq * 8 + e][j] = c.s[e];
    }
    __syncthreads();

    f32x4 acc[2][3];                            // [mt:i][ndt:d]
    #pragma unroll
    for (int mt = 0; mt < 2; mt++)
        #pragma unroll
        for (int nd = 0; nd < 3; nd++) acc[mt][nd] = (f32x4){0.f,0.f,0.f,0.f};
    #pragma unroll
    for (int kk = 0; kk < 2; kk++) {
        frag16 af[2];
        #pragma unroll
        for (int mt = 0; mt < 2; mt++)
            af[mt] = *(const frag16*)(&Aat[wm * 32 + mt * 16 + fr][kk * 32 + q * 8]);
        #pragma unroll
        for (int nd = 0; nd < 3; nd++) {
            frag16 bf = *(const frag16*)(&VtT[wn * 48 + nd * 16 + fr][kk * 32 + q * 8]);
            #pragma unroll
            for (int mt = 0; mt < 2; mt++)
                acc[mt][nd] = __builtin_amdgcn_mfma_f32_16x16x32_bf16(
                    af[mt], bf, acc[mt][nd], 0, 0, 0);
        }
    }

    const int h = g >> 10, b = (g >> 8) & 3, n = g & 255;
    #pragma unroll
    for (int nd = 0; nd < 3; nd++) {
        const int d = wn * 48 + nd * 16 + fr;
        #pragma unroll
        for (int mt = 0; mt < 2; mt++) {
            #pragma unroll
            for (int r = 0; r < 4; r++) {
                const int i = wm * 32 + mt * 16 + q * 4 + r;
                const int hr = ((n >> 4) << 3) | (i >> 3);
                const int wc = ((n & 15) << 3) | (i & 7);
                const size_t t = ((size_t)b << 14) + (size_t)hr * 128 + wc;
                const size_t off = t * HID + (size_t)h * HD + d;
                y_img[off] = f2b(acc[mt][nd][r] * b2f(y_img[off]));
            }
        }
    }
}

// ---------------- kernel 3: out_proj + bias + scatter (m97 structure) ------
__global__ __launch_bounds__(256) void k_outproj(
    const unsigned short* __restrict__ avy,     // (MTOK,HID) bf16 (=y_img)
    const unsigned short* __restrict__ woutT,   // (512, 768) bf16
    const float* __restrict__ b_out,            // (512) fp32
    const int* __restrict__ idx,
    float* __restrict__ out) {                  // (B,HW,C) fp32
    __shared__ alignas(16) unsigned short smem[4096 + 4096];  // A 8KB + B 8KB
    const int tid = threadIdx.x;
    const int wv = tid >> 6, lane = tid & 63;
    const int wm = wv >> 1, wn = wv & 1;
    const int fr = lane & 15, q = lane >> 4;
    const int c0 = blockIdx.x * 128;
    const int m0 = blockIdx.y * 128;

    const char* gbase[4];
    unsigned short* lbase[4];
    #pragma unroll
    for (int ci = 0; ci < 4; ci++) {
        int c = wv * 4 + ci;
        if (c < 8) {
            int row = c * 16 + (lane >> 2);
            gbase[ci] = (const char*)(avy + (size_t)(m0 + row) * HID + (lane & 3) * 8);
            lbase[ci] = smem + c * 512;
        } else {
            int cb = c - 8;
            int row = cb * 16 + (lane >> 2);
            gbase[ci] = (const char*)(woutT + (size_t)(c0 + row) * HID + (lane & 3) * 8);
            lbase[ci] = smem + 4096 + cb * 512;
        }
    }

    f32x4 acc[4][4];
    #pragma unroll
    for (int nt = 0; nt < 4; nt++)
        #pragma unroll
        for (int mt = 0; mt < 4; mt++) acc[nt][mt] = (f32x4){0.f,0.f,0.f,0.f};

    for (int k0 = 0; k0 < HID; k0 += 32) {
        #pragma unroll
        for (int ci = 0; ci < 4; ci++)
            gl2lds16(gbase[ci] + (size_t)k0 * 2, lbase[ci]);
        __syncthreads();
        frag16 af[4];
        #pragma unroll
        for (int mt = 0; mt < 4; mt++)
            af[mt] = *(const frag16*)(smem + (wm * 64 + mt * 16 + fr) * 32 + q * 8);
        #pragma unroll
        for (int nt = 0; nt < 4; nt++) {
            frag16 bf = *(const frag16*)(smem + 4096 +
                                         (wn * 64 + nt * 16 + fr) * 32 + q * 8);
            #pragma unroll
            for (int mt = 0; mt < 4; mt++)
                acc[nt][mt] = __builtin_amdgcn_mfma_f32_16x16x32_bf16(
                    af[mt], bf, acc[nt][mt], 0, 0, 0);
        }
        __syncthreads();
    }

    #pragma unroll
    for (int nt = 0; nt < 4; nt++) {
        const int c = c0 + wn * 64 + nt * 16 + fr;
        const float bo = b_out[c];
        #pragma unroll
        for (int mt = 0; mt < 4; mt++) {
            #pragma unroll
            for (int r = 0; r < 4; r++) {
                const int t = m0 + wm * 64 + mt * 16 + q * 4 + r;
                const int bb = t >> 14, hw = t & 16383;
                const int dst = idx[hw];
                out[((size_t)bb * HWTOK + dst) * Cc + c] = acc[nt][mt][r] + bo;
            }
        }
    }
}

extern "C" void kernel_launch(void* const* d_in, const int* in_sizes, int n_in,
                              void* d_out, int out_size, void* d_ws, size_t ws_size,
                              hipStream_t stream) {
    const float* x     = (const float*)d_in[0];
    const float* attnw = (const float*)d_in[1];
    const float* W_in  = (const float*)d_in[2];
    const float* b_in  = (const float*)d_in[3];
    const float* W_out = (const float*)d_in[4];
    const float* b_out = (const float*)d_in[5];
    const int*   idx   = (const int*)d_in[6];
    float*       out   = (float*)d_out;

    // workspace carve-up (~204.5 MB)
    char* p = (char*)d_ws;
    unsigned short* winT  = (unsigned short*)p; p += (size_t)N3 * Cc * 2;
    unsigned short* woutT = (unsigned short*)p; p += (size_t)Cc * HID * 2;
    unsigned short* vt    = (unsigned short*)p; p += (size_t)HEADS * Bb * NBT * BS2 * HD * 2;
    unsigned short* y_img = (unsigned short*)p; p += (size_t)MTOK * HID * 2;
    // xg (67 MB bf16) lives in d_out — dead until k_outproj writes it
    unsigned short* xg = (unsigned short*)d_out;

    k_transpose<<<(N3 * Cc + 255) / 256, 256, 0, stream>>>(W_in, winT, Cc, N3);
    k_transpose<<<(HID * Cc + 255) / 256, 256, 0, stream>>>(W_out, woutT, HID, Cc);
    k_gather<<<MTOK * 64 / 256, 256, 0, stream>>>(x, idx, xg);

    dim3 g1(HID / 64, MTOK / 128);  // (12, 512)
    k_inproj<<<g1, 256, 0, stream>>>(xg, winT, b_in, y_img, vt);

    k_attn<<<HEADS * Bb * NBT, 256, 0, stream>>>(attnw, vt, y_img);

    dim3 g3(Cc / 128, MTOK / 128);  // (4, 512)
    k_outproj<<<g3, 256, 0, stream>>>(y_img, woutT, b_out, idx, out);
}